// Round 1
// baseline (5260.628 us; speedup 1.0000x reference)
//
#include <hip/hip_runtime.h>
#include <cstdint>
#include <cstddef>

#define H 450
#define H2 900
#define NMESS 10241
#define NNODE 5120
#define KM 5
#define KN 6

// ---------------- tiled fp32 GEMM ----------------
#define BM 64
#define BN 64
#define BK 16

template<int ACT>  // 0 = none, 1 = relu
__global__ __launch_bounds__(256)
void gemm_f32(const float* __restrict__ A, const int* __restrict__ aidx, int lda,
              const float* __restrict__ B, int ldb,
              const float* __restrict__ bias,
              float* __restrict__ C, int ldc,
              int M, int N, int K)
{
  __shared__ float As[BK][BM + 1];
  __shared__ float Bs[BK][BN + 1];
  const int tid = threadIdx.x;
  const int bm = blockIdx.y * BM;
  const int bn = blockIdx.x * BN;
  const int tx = tid & 15;
  const int ty = tid >> 4;

  float acc[4][4] = {};

  const int r  = tid >> 2;        // 0..63 : A row within tile
  const int cs = (tid & 3) << 2;  // 0,4,8,12 : A col segment
  const int arow = bm + r;
  const float* Ap = nullptr;
  if (arow < M) {
    int pr = aidx ? aidx[arow] : arow;
    Ap = A + (size_t)pr * lda;
  }
  const int bc  = tid & 63;
  const int kr0 = tid >> 6;       // 0..3

  for (int k0 = 0; k0 < K; k0 += BK) {
#pragma unroll
    for (int i = 0; i < 4; ++i) {
      int k = cs + i;
      float v = 0.f;
      if (Ap && (k0 + k) < K) v = Ap[k0 + k];
      As[k][r] = v;
    }
#pragma unroll
    for (int i = 0; i < 4; ++i) {
      int kr = kr0 + (i << 2);
      float v = 0.f;
      int kk = k0 + kr, nn = bn + bc;
      if (kk < K && nn < N) v = B[(size_t)kk * ldb + nn];
      Bs[kr][bc] = v;
    }
    __syncthreads();
#pragma unroll
    for (int kk = 0; kk < BK; ++kk) {
      float a[4], b[4];
#pragma unroll
      for (int i = 0; i < 4; ++i) a[i] = As[kk][ty * 4 + i];
#pragma unroll
      for (int j = 0; j < 4; ++j) b[j] = Bs[kk][tx * 4 + j];
#pragma unroll
      for (int i = 0; i < 4; ++i)
#pragma unroll
        for (int j = 0; j < 4; ++j)
          acc[i][j] = fmaf(a[i], b[j], acc[i][j]);
    }
    __syncthreads();
  }

#pragma unroll
  for (int i = 0; i < 4; ++i) {
    int row = bm + ty * 4 + i;
    if (row >= M) continue;
#pragma unroll
    for (int j = 0; j < 4; ++j) {
      int col = bn + tx * 4 + j;
      if (col >= N) continue;
      float v = acc[i][j];
      if (bias) v += bias[col];
      if (ACT == 1) v = fmaxf(v, 0.f);
      C[(size_t)row * ldc + col] = v;
    }
  }
}

// ---------------- elementwise / gather kernels ----------------

__device__ __forceinline__ float sigmoidf_(float x) {
  return 1.f / (1.f + __expf(-x));
}

__global__ void k_build_idx(const int* __restrict__ fnode,
                            const int* __restrict__ fmess,
                            int* __restrict__ idxM) {
  int m = blockIdx.x * blockDim.x + threadIdx.x;
  if (m < NMESS) idxM[m] = fnode[fmess[m]];
}

// sum_h[m] = sum_k h[mess_graph[m,k]]
__global__ void k_gather_sum(const float* __restrict__ h,
                             const int* __restrict__ mg,
                             float* __restrict__ sum_h) {
  int m = blockIdx.y;
  int j = blockIdx.x * blockDim.x + threadIdx.x;
  if (j >= H) return;
  const int* e = mg + (size_t)m * KM;
  float s = 0.f;
#pragma unroll
  for (int k = 0; k < KM; ++k)
    s += h[(size_t)e[k] * H + j];
  sum_h[(size_t)m * H + j] = s;
}

// sum_gh[m] = sum_k sigmoid(r1b[m] + g[e]) * h[e]
__global__ void k_gather_gsum(const float* __restrict__ h,
                              const float* __restrict__ g,
                              const float* __restrict__ r1b,
                              const int* __restrict__ mg,
                              float* __restrict__ sum_gh) {
  int m = blockIdx.y;
  int j = blockIdx.x * blockDim.x + threadIdx.x;
  if (j >= H) return;
  const int* e = mg + (size_t)m * KM;
  float rb = r1b[(size_t)m * H + j];
  float s = 0.f;
#pragma unroll
  for (int k = 0; k < KM; ++k) {
    size_t o = (size_t)e[k] * H + j;
    float rr = sigmoidf_(rb + g[o]);
    s += rr * h[o];
  }
  sum_gh[(size_t)m * H + j] = s;
}

// h = mask * ((1-z)*sum_h + z*pre_h), in place (h not read here)
__global__ void k_combine(const float* __restrict__ c_z,
                          const float* __restrict__ t_z,
                          const float* __restrict__ c_h,
                          const float* __restrict__ t_h,
                          const float* __restrict__ sum_h,
                          float* __restrict__ h) {
  int m = blockIdx.y;
  int j = blockIdx.x * blockDim.x + threadIdx.x;
  if (j >= H) return;
  size_t o = (size_t)m * H + j;
  float z  = sigmoidf_(c_z[o] + t_z[o]);
  float ph = tanhf(c_h[o] + t_h[o]);
  float v  = (1.f - z) * sum_h[o] + z * ph;
  h[o] = (m == 0) ? 0.f : v;
}

// Acat[n, 0:450] = emb[fnode[n]] ; Acat[n, 450:900] = sum_k h[node_graph[n,k]]
__global__ void k_nodecat(const float* __restrict__ emb,
                          const int* __restrict__ fnode,
                          const float* __restrict__ h,
                          const int* __restrict__ ng,
                          float* __restrict__ Acat) {
  int n = blockIdx.y;
  int j = blockIdx.x * blockDim.x + threadIdx.x;
  if (j >= H) return;
  Acat[(size_t)n * H2 + j] = emb[(size_t)fnode[n] * H + j];
  const int* e = ng + (size_t)n * KN;
  float s = 0.f;
#pragma unroll
  for (int k = 0; k < KN; ++k)
    s += h[(size_t)e[k] * H + j];
  Acat[(size_t)n * H2 + H + j] = s;
}

// ---------------- launch ----------------

extern "C" void kernel_launch(void* const* d_in, const int* in_sizes, int n_in,
                              void* d_out, int out_size, void* d_ws, size_t ws_size,
                              hipStream_t stream) {
  (void)in_sizes; (void)n_in; (void)out_size; (void)ws_size;

  const int*   fnode      = (const int*)d_in[0];
  const int*   fmess      = (const int*)d_in[1];
  const int*   node_graph = (const int*)d_in[2];
  const int*   mess_graph = (const int*)d_in[3];
  const float* emb        = (const float*)d_in[4];
  const float* Wz         = (const float*)d_in[5];
  const float* bz         = (const float*)d_in[6];
  const float* Wr         = (const float*)d_in[7];
  const float* Ur         = (const float*)d_in[8];
  const float* bu         = (const float*)d_in[9];
  const float* Wh         = (const float*)d_in[10];
  const float* bh         = (const float*)d_in[11];
  const float* Wo         = (const float*)d_in[12];
  const float* bo         = (const float*)d_in[13];

  const size_t Msz = (size_t)NMESS * H;   // 4,608,450 elements
  float* W      = (float*)d_ws;
  float* h      = W;                 // M x H (in-place updated)
  float* c_z    = W + 1 * Msz;       // loop-invariant fmess_e@Wz_top + bz
  float* c_h    = W + 2 * Msz;
  float* r1b    = W + 3 * Msz;       // fmess_e@Wr + bu
  float* sum_h  = W + 4 * Msz;
  float* g      = W + 5 * Msz;       // h@Ur ; reused for t_h
  float* sum_gh = W + 6 * Msz;       // reused for t_z
  int*   idxM   = (int*)(W + 7 * Msz);
  float* Acat   = c_z;               // reuse after GRU (N*900 <= Msz)

  hipMemsetAsync(h, 0, Msz * sizeof(float), stream);
  k_build_idx<<<(NMESS + 255) / 256, 256, 0, stream>>>(fnode, fmess, idxM);

  dim3 gB((H + BN - 1) / BN, (NMESS + BM - 1) / BM);
  // loop-invariant precompute: A = emb gathered via idxM
  gemm_f32<0><<<gB, 256, 0, stream>>>(emb, idxM, H, Wz, H, bz, c_z, H, NMESS, H, H);
  gemm_f32<0><<<gB, 256, 0, stream>>>(emb, idxM, H, Wh, H, bh, c_h, H, NMESS, H, H);
  gemm_f32<0><<<gB, 256, 0, stream>>>(emb, idxM, H, Wr, H, bu, r1b, H, NMESS, H, H);

  dim3 gE(2, NMESS);
  for (int d = 0; d < 8; ++d) {
    k_gather_sum<<<gE, 256, 0, stream>>>(h, mess_graph, sum_h);
    gemm_f32<0><<<gB, 256, 0, stream>>>(h, nullptr, H, Ur, H, nullptr, g, H, NMESS, H, H);
    k_gather_gsum<<<gE, 256, 0, stream>>>(h, g, r1b, mess_graph, sum_gh);
    // t_h = sum_gh @ Wh_bottom  -> overwrite g (dead)
    gemm_f32<0><<<gB, 256, 0, stream>>>(sum_gh, nullptr, H, Wh + (size_t)H * H, H, nullptr, g, H, NMESS, H, H);
    // t_z = sum_h @ Wz_bottom   -> overwrite sum_gh (dead)
    gemm_f32<0><<<gB, 256, 0, stream>>>(sum_h, nullptr, H, Wz + (size_t)H * H, H, nullptr, sum_gh, H, NMESS, H, H);
    k_combine<<<gE, 256, 0, stream>>>(c_z, sum_gh, c_h, g, sum_h, h);
  }

  dim3 gN(2, NNODE);
  k_nodecat<<<gN, 256, 0, stream>>>(emb, fnode, h, node_graph, Acat);
  dim3 gF((H + BN - 1) / BN, (NNODE + BM - 1) / BM);
  gemm_f32<1><<<gF, 256, 0, stream>>>(Acat, nullptr, H2, Wo, H, bo, (float*)d_out, H, NNODE, H, H2);

  // messages output = zeros
  hipMemsetAsync((float*)d_out + (size_t)NNODE * H, 0, Msz * sizeof(float), stream);
}

// Round 3
// 2488.147 us; speedup vs baseline: 2.1143x; 2.1143x over previous
//
#include <hip/hip_runtime.h>
#include <cstdint>
#include <cstddef>

#define H 450
#define H2 900
#define KP 480
#define KP2 960
#define NMESS 10241
#define NNODE 5120
#define KM 5
#define KN 6

typedef __attribute__((ext_vector_type(8))) short short8;   // 8 bf16
typedef __attribute__((ext_vector_type(4))) float f32x4;

__device__ __forceinline__ short bf16rne(float f) {
  union { float f; unsigned u; } x; x.f = f;
  unsigned u = x.u;
  u += 0x7FFF + ((u >> 16) & 1);
  return (short)(u >> 16);
}
__device__ __forceinline__ float bf16tof(short s) {
  union { float f; unsigned u; } x;
  x.u = ((unsigned)(unsigned short)s) << 16;
  return x.f;
}
__device__ __forceinline__ void bf16split(float v, short& hi, short& lo) {
  hi = bf16rne(v);
  lo = bf16rne(v - bf16tof(hi));
}

// ---------------- split-bf16 MFMA GEMM (3-product, ~fp32 precision) ----------
// C[M,N] = act(gather(A)[M,Kreal] @ Bt^T + bias)
// A: f32 row-major, lda floats, optional row gather via aidx.
// Bt_hi/Bt_lo: bf16 [512+][Kpad], row c = column c of original B, zero-padded.
#define BM 128
#define BN 64
#define BK 32
#define LDS_A 40   // BK + 8 halves padding (80B row stride, 16B aligned)

template<int ACT>  // 0 = none, 1 = relu
__global__ __launch_bounds__(256)
void gemm_bf16s(const float* __restrict__ A, const int* __restrict__ aidx,
                int lda, int Kreal,
                const short* __restrict__ Bth, const short* __restrict__ Btl,
                int Kpad,
                const float* __restrict__ bias,
                float* __restrict__ C, int ldc, int M, int N)
{
  __shared__ short Ash[BM][LDS_A];
  __shared__ short Asl[BM][LDS_A];
  __shared__ short Bsh[BN][LDS_A];
  __shared__ short Bsl[BN][LDS_A];
  const int tid  = threadIdx.x;
  const int bm   = blockIdx.y * BM;
  const int bn   = blockIdx.x * BN;
  const int lane = tid & 63;
  const int wid  = tid >> 6;
  const int wm   = (wid >> 1) * 64;   // wave row offset
  const int wn   = (wid & 1) * 32;    // wave col offset
  const int l15  = lane & 15;
  const int lk8  = (lane >> 4) * 8;   // k sub-offset (halves)

  // A staging: thread -> row ar (0..127), half-range [ac, ac+16)
  const int ar = tid >> 1;
  const int ac = (tid & 1) * 16;
  int arow = bm + ar; if (arow >= M) arow = M - 1;
  if (aidx) arow = aidx[arow];
  const float* Ap = A + (size_t)arow * lda;

  // B staging: row br (0..63), half-range [bc, bc+8)
  const int br = tid >> 2;
  const int bc = (tid & 3) * 8;
  const size_t boff = (size_t)(bn + br) * Kpad;

  f32x4 acc[4][2];
#pragma unroll
  for (int i = 0; i < 4; ++i)
#pragma unroll
    for (int j = 0; j < 2; ++j)
#pragma unroll
      for (int r = 0; r < 4; ++r) acc[i][j][r] = 0.f;

  for (int k0 = 0; k0 < Kpad; k0 += BK) {
    // ---- stage A: load 16 f32, split -> hi/lo bf16, 16B LDS writes ----
    short8 ph0, pl0, ph1, pl1;
#pragma unroll
    for (int j = 0; j < 4; ++j) {
      int k = k0 + ac + j * 2;
      float v0 = 0.f, v1 = 0.f;
      if (k + 1 < Kreal) { float2 v = *(const float2*)&Ap[k]; v0 = v.x; v1 = v.y; }
      else if (k < Kreal) { v0 = Ap[k]; }
      short h0, l0, h1, l1;
      bf16split(v0, h0, l0); bf16split(v1, h1, l1);
      ph0[j*2] = h0; ph0[j*2+1] = h1; pl0[j*2] = l0; pl0[j*2+1] = l1;
    }
#pragma unroll
    for (int j = 0; j < 4; ++j) {
      int k = k0 + ac + 8 + j * 2;
      float v0 = 0.f, v1 = 0.f;
      if (k + 1 < Kreal) { float2 v = *(const float2*)&Ap[k]; v0 = v.x; v1 = v.y; }
      else if (k < Kreal) { v0 = Ap[k]; }
      short h0, l0, h1, l1;
      bf16split(v0, h0, l0); bf16split(v1, h1, l1);
      ph1[j*2] = h0; ph1[j*2+1] = h1; pl1[j*2] = l0; pl1[j*2+1] = l1;
    }
    *(short8*)&Ash[ar][ac]     = ph0;
    *(short8*)&Ash[ar][ac + 8] = ph1;
    *(short8*)&Asl[ar][ac]     = pl0;
    *(short8*)&Asl[ar][ac + 8] = pl1;
    // ---- stage B: straight bf16 16B copies (pre-padded, no bounds) ----
    *(short8*)&Bsh[br][bc] = *(const short8*)&Bth[boff + k0 + bc];
    *(short8*)&Bsl[br][bc] = *(const short8*)&Btl[boff + k0 + bc];
    __syncthreads();

    short8 ah[4], al[4], bh[2], bl[2];
#pragma unroll
    for (int i = 0; i < 4; ++i) {
      ah[i] = *(const short8*)&Ash[wm + i*16 + l15][lk8];
      al[i] = *(const short8*)&Asl[wm + i*16 + l15][lk8];
    }
#pragma unroll
    for (int j = 0; j < 2; ++j) {
      bh[j] = *(const short8*)&Bsh[wn + j*16 + l15][lk8];
      bl[j] = *(const short8*)&Bsl[wn + j*16 + l15][lk8];
    }
#pragma unroll
    for (int i = 0; i < 4; ++i)
#pragma unroll
      for (int j = 0; j < 2; ++j) {
        acc[i][j] = __builtin_amdgcn_mfma_f32_16x16x32_bf16(ah[i], bh[j], acc[i][j], 0, 0, 0);
        acc[i][j] = __builtin_amdgcn_mfma_f32_16x16x32_bf16(al[i], bh[j], acc[i][j], 0, 0, 0);
        acc[i][j] = __builtin_amdgcn_mfma_f32_16x16x32_bf16(ah[i], bl[j], acc[i][j], 0, 0, 0);
      }
    __syncthreads();
  }

  // epilogue: col = bn+wn+j*16+l15 ; row = bm+wm+i*16+(lane>>4)*4+r
  const int rr0 = (lane >> 4) * 4;
#pragma unroll
  for (int j = 0; j < 2; ++j) {
    int col = bn + wn + j*16 + l15;
    if (col >= N) continue;
    float bv = bias ? bias[col] : 0.f;
#pragma unroll
    for (int i = 0; i < 4; ++i) {
      int row0 = bm + wm + i*16 + rr0;
#pragma unroll
      for (int r = 0; r < 4; ++r) {
        int row = row0 + r;
        if (row >= M) continue;
        float v = acc[i][j][r] + bv;
        if (ACT == 1) v = fmaxf(v, 0.f);
        C[(size_t)row * ldc + col] = v;
      }
    }
  }
}

// ---------------- weight transpose + bf16 hi/lo split ----------------
// W: [Kreal][450] f32 row-major -> Bt_hi/lo: [512][Kpad] bf16, Bt[c][k]=W[k][c]
__global__ __launch_bounds__(256)
void k_wT(const float* __restrict__ W, int Kreal,
          short* __restrict__ Bth, short* __restrict__ Btl, int Kpad) {
  __shared__ float T[32][33];
  const int tx = threadIdx.x & 31;
  const int ty = threadIdx.x >> 5;   // 0..7
  const int k0 = blockIdx.x * 32;
  const int c0 = blockIdx.y * 32;
#pragma unroll
  for (int i = 0; i < 4; ++i) {
    int k = k0 + ty + i * 8, c = c0 + tx;
    T[ty + i*8][tx] = (k < Kreal && c < H) ? W[(size_t)k * H + c] : 0.f;
  }
  __syncthreads();
#pragma unroll
  for (int i = 0; i < 4; ++i) {
    int c = c0 + ty + i * 8, k = k0 + tx;
    if (k < Kpad) {
      short hi, lo;
      bf16split(T[tx][ty + i*8], hi, lo);
      Bth[(size_t)c * Kpad + k] = hi;
      Btl[(size_t)c * Kpad + k] = lo;
    }
  }
}

// ---------------- elementwise / gather kernels (all f32) ----------------

__device__ __forceinline__ float sigmoidf_(float x) {
  return 1.f / (1.f + __expf(-x));
}

__global__ void k_build_idx(const int* __restrict__ fnode,
                            const int* __restrict__ fmess,
                            int* __restrict__ idxM) {
  int m = blockIdx.x * blockDim.x + threadIdx.x;
  if (m < NMESS) idxM[m] = fnode[fmess[m]];
}

__global__ void k_gather_sum(const float* __restrict__ h,
                             const int* __restrict__ mg,
                             float* __restrict__ sum_h) {
  int m = blockIdx.y;
  int j = blockIdx.x * blockDim.x + threadIdx.x;
  if (j >= H) return;
  const int* e = mg + (size_t)m * KM;
  float s = 0.f;
#pragma unroll
  for (int k = 0; k < KM; ++k)
    s += h[(size_t)e[k] * H + j];
  sum_h[(size_t)m * H + j] = s;
}

__global__ void k_gather_gsum(const float* __restrict__ h,
                              const float* __restrict__ g,
                              const float* __restrict__ r1b,
                              const int* __restrict__ mg,
                              float* __restrict__ sum_gh) {
  int m = blockIdx.y;
  int j = blockIdx.x * blockDim.x + threadIdx.x;
  if (j >= H) return;
  const int* e = mg + (size_t)m * KM;
  float rb = r1b[(size_t)m * H + j];
  float s = 0.f;
#pragma unroll
  for (int k = 0; k < KM; ++k) {
    size_t o = (size_t)e[k] * H + j;
    float rr = sigmoidf_(rb + g[o]);
    s += rr * h[o];
  }
  sum_gh[(size_t)m * H + j] = s;
}

// h_out = mask * ((1-z)*sum_h + z*pre_h); tz aliases h_out (same offset RAW, ok)
__global__ void k_combine(const float* __restrict__ c_z,
                          const float* tz,
                          const float* __restrict__ c_h,
                          const float* __restrict__ th,
                          const float* __restrict__ sum_h,
                          float* h) {
  int m = blockIdx.y;
  int j = blockIdx.x * blockDim.x + threadIdx.x;
  if (j >= H) return;
  size_t o = (size_t)m * H + j;
  float z  = sigmoidf_(c_z[o] + tz[o]);
  float ph = tanhf(c_h[o] + th[o]);
  float v  = (1.f - z) * sum_h[o] + z * ph;
  h[o] = (m == 0) ? 0.f : v;
}

__global__ void k_nodecat(const float* __restrict__ emb,
                          const int* __restrict__ fnode,
                          const float* __restrict__ h,
                          const int* __restrict__ ng,
                          float* __restrict__ Acat) {
  int n = blockIdx.y;
  int j = blockIdx.x * blockDim.x + threadIdx.x;
  if (j >= H) return;
  Acat[(size_t)n * H2 + j] = emb[(size_t)fnode[n] * H + j];
  const int* e = ng + (size_t)n * KN;
  float s = 0.f;
#pragma unroll
  for (int k = 0; k < KN; ++k)
    s += h[(size_t)e[k] * H + j];
  Acat[(size_t)n * H2 + H + j] = s;
}

// ---------------- launch ----------------

extern "C" void kernel_launch(void* const* d_in, const int* in_sizes, int n_in,
                              void* d_out, int out_size, void* d_ws, size_t ws_size,
                              hipStream_t stream) {
  (void)in_sizes; (void)n_in; (void)out_size; (void)ws_size;

  const int*   fnode      = (const int*)d_in[0];
  const int*   fmess      = (const int*)d_in[1];
  const int*   node_graph = (const int*)d_in[2];
  const int*   mess_graph = (const int*)d_in[3];
  const float* emb        = (const float*)d_in[4];
  const float* Wz         = (const float*)d_in[5];
  const float* bz         = (const float*)d_in[6];
  const float* Wr         = (const float*)d_in[7];
  const float* Ur         = (const float*)d_in[8];
  const float* bu         = (const float*)d_in[9];
  const float* Wh         = (const float*)d_in[10];
  const float* bh         = (const float*)d_in[11];
  const float* Wo         = (const float*)d_in[12];
  const float* bo         = (const float*)d_in[13];

  const size_t Msz = (size_t)NMESS * H;   // 4,608,450
  float* W      = (float*)d_ws;
  float* h      = W;                 // also holds t_z late in each step
  float* c_z    = W + 1 * Msz;
  float* c_h    = W + 2 * Msz;
  float* r1b    = W + 3 * Msz;
  float* sum_h  = W + 4 * Msz;
  float* g      = W + 5 * Msz;       // h@Ur ; reused for t_h
  float* sum_gh = W + 6 * Msz;       // reused for Acat after the loop
  float* Acat   = sum_gh;            // [NNODE][900] = 4,608,000 <= Msz

  // bf16 hi/lo weights + idx live in the messages region of d_out (wiped last).
  // Sizes: 6 * 2 * 512*480 + 2 * 512*960 = 3,932,160 halves = 7.86 MB < 18.4 MB
  short* scr    = (short*)((float*)d_out + (size_t)NNODE * H);
  short* BtWzTh = scr;                 short* BtWzTl = BtWzTh + 512 * KP;
  short* BtWhTh = BtWzTl + 512 * KP;   short* BtWhTl = BtWhTh + 512 * KP;
  short* BtWrh  = BtWhTl + 512 * KP;   short* BtWrl  = BtWrh  + 512 * KP;
  short* BtUrh  = BtWrl  + 512 * KP;   short* BtUrl  = BtUrh  + 512 * KP;
  short* BtWzBh = BtUrl  + 512 * KP;   short* BtWzBl = BtWzBh + 512 * KP;
  short* BtWhBh = BtWzBl + 512 * KP;   short* BtWhBl = BtWhBh + 512 * KP;
  short* BtWoh  = BtWhBl + 512 * KP;   short* BtWol  = BtWoh  + 512 * KP2;
  int*   idxM   = (int*)(BtWol + 512 * KP2);

  hipMemsetAsync(h, 0, Msz * sizeof(float), stream);
  k_build_idx<<<(NMESS + 255) / 256, 256, 0, stream>>>(fnode, fmess, idxM);

  // weight transposes (bf16 hi/lo, zero-padded)
  dim3 gT(KP / 32, 16), gT2(KP2 / 32, 16);
  k_wT<<<gT,  256, 0, stream>>>(Wz,                  H, BtWzTh, BtWzTl, KP);
  k_wT<<<gT,  256, 0, stream>>>(Wz + (size_t)H * H,  H, BtWzBh, BtWzBl, KP);
  k_wT<<<gT,  256, 0, stream>>>(Wh,                  H, BtWhTh, BtWhTl, KP);
  k_wT<<<gT,  256, 0, stream>>>(Wh + (size_t)H * H,  H, BtWhBh, BtWhBl, KP);
  k_wT<<<gT,  256, 0, stream>>>(Wr,                  H, BtWrh,  BtWrl,  KP);
  k_wT<<<gT,  256, 0, stream>>>(Ur,                  H, BtUrh,  BtUrl,  KP);
  k_wT<<<gT2, 256, 0, stream>>>(Wo,                 H2, BtWoh,  BtWol,  KP2);

  dim3 gB(8, (NMESS + BM - 1) / BM);   // (8, 81)
  // loop-invariant precompute (A = emb rows gathered via idxM)
  gemm_bf16s<0><<<gB, 256, 0, stream>>>(emb, idxM, H, H, BtWzTh, BtWzTl, KP, bz, c_z, H, NMESS, H);
  gemm_bf16s<0><<<gB, 256, 0, stream>>>(emb, idxM, H, H, BtWhTh, BtWhTl, KP, bh, c_h, H, NMESS, H);
  gemm_bf16s<0><<<gB, 256, 0, stream>>>(emb, idxM, H, H, BtWrh,  BtWrl,  KP, bu, r1b, H, NMESS, H);

  dim3 gE(2, NMESS);
  for (int d = 0; d < 8; ++d) {
    k_gather_sum<<<gE, 256, 0, stream>>>(h, mess_graph, sum_h);
    gemm_bf16s<0><<<gB, 256, 0, stream>>>(h, nullptr, H, H, BtUrh, BtUrl, KP, nullptr, g, H, NMESS, H);
    k_gather_gsum<<<gE, 256, 0, stream>>>(h, g, r1b, mess_graph, sum_gh);
    // t_h -> g (g dead), t_z -> h (old h dead)
    gemm_bf16s<0><<<gB, 256, 0, stream>>>(sum_gh, nullptr, H, H, BtWhBh, BtWhBl, KP, nullptr, g, H, NMESS, H);
    gemm_bf16s<0><<<gB, 256, 0, stream>>>(sum_h,  nullptr, H, H, BtWzBh, BtWzBl, KP, nullptr, h, H, NMESS, H);
    k_combine<<<gE, 256, 0, stream>>>(c_z, h, c_h, g, sum_h, h);
  }

  dim3 gN(2, NNODE);
  k_nodecat<<<gN, 256, 0, stream>>>(emb, fnode, h, node_graph, Acat);
  dim3 gF(8, NNODE / BM);              // (8, 40)
  gemm_bf16s<1><<<gF, 256, 0, stream>>>(Acat, nullptr, H2, H2, BtWoh, BtWol, KP2, bo, (float*)d_out, H, NNODE, H);

  // messages output = zeros (also wipes the weight scratch) — AFTER final GEMM
  hipMemsetAsync((float*)d_out + (size_t)NNODE * H, 0, Msz * sizeof(float), stream);
}

// Round 4
// 2005.399 us; speedup vs baseline: 2.6232x; 1.2407x over previous
//
#include <hip/hip_runtime.h>
#include <cstdint>
#include <cstddef>

#define H 450
#define H2 900
#define KP 480
#define KP2 960
#define NMESS 10241
#define NNODE 5120
#define MPAD 10368           // 81 * 128, row padding for GEMM tiles
#define PSZ ((size_t)MPAD * KP)   // plane size in shorts = 4,976,640
#define KM 5
#define KN 6

typedef __attribute__((ext_vector_type(8))) short short8;   // 8 bf16
typedef __attribute__((ext_vector_type(4))) float f32x4;

__device__ __forceinline__ short bf16rne(float f) {
  union { float f; unsigned u; } x; x.f = f;
  unsigned u = x.u;
  u += 0x7FFF + ((u >> 16) & 1);
  return (short)(u >> 16);
}
__device__ __forceinline__ float bf16tof(short s) {
  union { float f; unsigned u; } x;
  x.u = ((unsigned)(unsigned short)s) << 16;
  return x.f;
}
__device__ __forceinline__ void bf16split(float v, short& hi, short& lo) {
  hi = bf16rne(v);
  lo = bf16rne(v - bf16tof(hi));
}
__device__ __forceinline__ float sigmoidf_(float x) {
  return 1.f / (1.f + __expf(-x));
}

// ---------------- split-bf16 MFMA GEMM v2 ----------------
// C = act(A @ Bt^T + bias), A pre-split hi/lo bf16 [rows][Kpad], zero-padded.
// Bt pre-split hi/lo bf16 [512+][Kpad]. Double-buffered LDS, 1 barrier/K-step.
#define BM 128
#define BN 64
#define BK 32
#define LDS_A 40   // BK + 8 halves padding

template<int ACT, int OUT>  // ACT: 0 none, 1 relu | OUT: 0 f32 C, 1 split planes
__global__ __launch_bounds__(256)
void gemm2(const short* __restrict__ Ah, const short* __restrict__ Al, int Kpad,
           const short* __restrict__ Bth, const short* __restrict__ Btl,
           const float* __restrict__ bias,
           float* C, short* Ch, short* Cl,
           int ldc, int M, int N)
{
  __shared__ short As[2][2][BM][LDS_A];   // [buf][plane][row][k] 40,960 B
  __shared__ short Bs[2][2][BN][LDS_A];   // 20,480 B
  const int tid  = threadIdx.x;
  const int lane = tid & 63;
  const int wid  = tid >> 6;
  const int bm   = blockIdx.y * BM;
  const int bn   = blockIdx.x * BN;
  const int wm   = (wid >> 1) * 64;
  const int wn   = (wid & 1) * 32;
  const int l15  = lane & 15;
  const int lk8  = (lane >> 4) * 8;
  const int ar   = tid >> 1;          // 0..127
  const int ac   = (tid & 1) * 16;    // 0,16
  const int br   = tid >> 2;          // 0..63
  const int bc   = (tid & 3) * 8;     // 0,8,16,24

  const short* Aph = Ah  + (size_t)(bm + ar) * Kpad + ac;
  const short* Apl = Al  + (size_t)(bm + ar) * Kpad + ac;
  const short* Bph = Bth + (size_t)(bn + br) * Kpad + bc;
  const short* Bpl = Btl + (size_t)(bn + br) * Kpad + bc;
  const int nk = Kpad / BK;

  f32x4 acc[4][2];
#pragma unroll
  for (int i = 0; i < 4; ++i)
#pragma unroll
    for (int j = 0; j < 2; ++j)
#pragma unroll
      for (int r = 0; r < 4; ++r) acc[i][j][r] = 0.f;

  short8 rah0, rah1, ral0, ral1, rbh, rbl;
  auto LOAD = [&](int t) {
    const int k = t * BK;
    rah0 = *(const short8*)&Aph[k];     rah1 = *(const short8*)&Aph[k + 8];
    ral0 = *(const short8*)&Apl[k];     ral1 = *(const short8*)&Apl[k + 8];
    rbh  = *(const short8*)&Bph[k];     rbl  = *(const short8*)&Bpl[k];
  };
  auto STORE = [&](int b) {
    *(short8*)&As[b][0][ar][ac]     = rah0;
    *(short8*)&As[b][0][ar][ac + 8] = rah1;
    *(short8*)&As[b][1][ar][ac]     = ral0;
    *(short8*)&As[b][1][ar][ac + 8] = ral1;
    *(short8*)&Bs[b][0][br][bc]     = rbh;
    *(short8*)&Bs[b][1][br][bc]     = rbl;
  };

  LOAD(0); STORE(0);
  __syncthreads();
  int cur = 0;
  for (int t = 0; t < nk; ++t) {
    if (t + 1 < nk) LOAD(t + 1);
    short8 ah[4], al[4], bh[2], bl[2];
#pragma unroll
    for (int i = 0; i < 4; ++i) {
      ah[i] = *(const short8*)&As[cur][0][wm + i*16 + l15][lk8];
      al[i] = *(const short8*)&As[cur][1][wm + i*16 + l15][lk8];
    }
#pragma unroll
    for (int j = 0; j < 2; ++j) {
      bh[j] = *(const short8*)&Bs[cur][0][wn + j*16 + l15][lk8];
      bl[j] = *(const short8*)&Bs[cur][1][wn + j*16 + l15][lk8];
    }
#pragma unroll
    for (int i = 0; i < 4; ++i)
#pragma unroll
      for (int j = 0; j < 2; ++j) {
        acc[i][j] = __builtin_amdgcn_mfma_f32_16x16x32_bf16(ah[i], bh[j], acc[i][j], 0, 0, 0);
        acc[i][j] = __builtin_amdgcn_mfma_f32_16x16x32_bf16(al[i], bh[j], acc[i][j], 0, 0, 0);
        acc[i][j] = __builtin_amdgcn_mfma_f32_16x16x32_bf16(ah[i], bl[j], acc[i][j], 0, 0, 0);
      }
    if (t + 1 < nk) STORE(cur ^ 1);
    __syncthreads();
    cur ^= 1;
  }

  const int rr0 = (lane >> 4) * 4;
#pragma unroll
  for (int j = 0; j < 2; ++j) {
    int col = bn + wn + j*16 + l15;
    if (col >= N) continue;
    float bv = bias ? bias[col] : 0.f;
#pragma unroll
    for (int i = 0; i < 4; ++i) {
      int row0 = bm + wm + i*16 + rr0;
#pragma unroll
      for (int r = 0; r < 4; ++r) {
        int row = row0 + r;
        if (row >= M) continue;
        float v = acc[i][j][r] + bv;
        if (ACT == 1) v = fmaxf(v, 0.f);
        if (OUT == 0) {
          C[(size_t)row * ldc + col] = v;
        } else {
          short hi, lo; bf16split(v, hi, lo);
          Ch[(size_t)row * ldc + col] = hi;
          Cl[(size_t)row * ldc + col] = lo;
        }
      }
    }
  }
}

// ---------------- weight transpose + bf16 hi/lo split ----------------
__global__ __launch_bounds__(256)
void k_wT(const float* __restrict__ W, int Kreal,
          short* __restrict__ Bth, short* __restrict__ Btl, int Kpad) {
  __shared__ float T[32][33];
  const int tx = threadIdx.x & 31;
  const int ty = threadIdx.x >> 5;
  const int k0 = blockIdx.x * 32;
  const int c0 = blockIdx.y * 32;
#pragma unroll
  for (int i = 0; i < 4; ++i) {
    int k = k0 + ty + i*8, c = c0 + tx;
    T[ty + i*8][tx] = (k < Kreal && c < H) ? W[(size_t)k * H + c] : 0.f;
  }
  __syncthreads();
#pragma unroll
  for (int i = 0; i < 4; ++i) {
    int c = c0 + ty + i*8, k = k0 + tx;
    if (k < Kpad) {
      short hi, lo;
      bf16split(T[tx][ty + i*8], hi, lo);
      Bth[(size_t)c * Kpad + k] = hi;
      Btl[(size_t)c * Kpad + k] = lo;
    }
  }
}

// ---------------- elementwise / gather kernels (×2 vectorized) ----------------

__global__ void k_build_idx(const int* __restrict__ fnode,
                            const int* __restrict__ fmess,
                            int* __restrict__ idxM) {
  int m = blockIdx.x * blockDim.x + threadIdx.x;
  if (m < NMESS) idxM[m] = fnode[fmess[m]];
}

// eS[m] = split(emb[idxM[m]])
__global__ void k_embsplit(const float* __restrict__ emb,
                           const int* __restrict__ idxM,
                           short* __restrict__ eh, short* __restrict__ el) {
  int m = blockIdx.x, j = threadIdx.x * 2;
  if (j >= H) return;
  float2 v = *(const float2*)&emb[(size_t)idxM[m] * H + j];
  short2 h2, l2;
  bf16split(v.x, h2.x, l2.x); bf16split(v.y, h2.y, l2.y);
  size_t o = (size_t)m * KP + j;
  *(short2*)&eh[o] = h2; *(short2*)&el[o] = l2;
}

// shS[m] = split( sum_k (hi+lo)[mg[m,k]] )
__global__ void k_gather_sum(const short* __restrict__ hh, const short* __restrict__ hl,
                             const int* __restrict__ mg,
                             short* __restrict__ oh, short* __restrict__ ol) {
  int m = blockIdx.x, j = threadIdx.x * 2;
  if (j >= H) return;
  const int* e = mg + (size_t)m * KM;
  float s0 = 0.f, s1 = 0.f;
#pragma unroll
  for (int k = 0; k < KM; ++k) {
    size_t o = (size_t)e[k] * KP + j;
    short2 ph = *(const short2*)&hh[o];
    short2 pl = *(const short2*)&hl[o];
    s0 += bf16tof(ph.x) + bf16tof(pl.x);
    s1 += bf16tof(ph.y) + bf16tof(pl.y);
  }
  short2 h2, l2;
  bf16split(s0, h2.x, l2.x); bf16split(s1, h2.y, l2.y);
  size_t o = (size_t)m * KP + j;
  *(short2*)&oh[o] = h2; *(short2*)&ol[o] = l2;
}

// ghS[m] = split( sum_k sigmoid(r1b[m] + g[e]) * h[e] )
__global__ void k_gather_gsum(const short* __restrict__ hh, const short* __restrict__ hl,
                              const float* __restrict__ g,
                              const float* __restrict__ r1b,
                              const int* __restrict__ mg,
                              short* __restrict__ oh, short* __restrict__ ol) {
  int m = blockIdx.x, j = threadIdx.x * 2;
  if (j >= H) return;
  const int* e = mg + (size_t)m * KM;
  float2 rb = *(const float2*)&r1b[(size_t)m * H + j];
  float s0 = 0.f, s1 = 0.f;
#pragma unroll
  for (int k = 0; k < KM; ++k) {
    size_t oP = (size_t)e[k] * KP + j;
    size_t o4 = (size_t)e[k] * H + j;
    float2 gv = *(const float2*)&g[o4];
    short2 ph = *(const short2*)&hh[oP];
    short2 pl = *(const short2*)&hl[oP];
    float h0 = bf16tof(ph.x) + bf16tof(pl.x);
    float h1 = bf16tof(ph.y) + bf16tof(pl.y);
    s0 += sigmoidf_(rb.x + gv.x) * h0;
    s1 += sigmoidf_(rb.y + gv.y) * h1;
  }
  short2 h2, l2;
  bf16split(s0, h2.x, l2.x); bf16split(s1, h2.y, l2.y);
  size_t o = (size_t)m * KP + j;
  *(short2*)&oh[o] = h2; *(short2*)&ol[o] = l2;
}

// h = mask*((1-z)*sum_h + z*tanh(c_h+th)); tz read from h-planes then overwritten
__global__ void k_combine(const float* __restrict__ c_z,
                          const float* __restrict__ c_h,
                          const float* __restrict__ th,
                          const short* __restrict__ shh, const short* __restrict__ shl,
                          short* hh, short* hl) {
  int m = blockIdx.x, j = threadIdx.x * 2;
  if (j >= H) return;
  size_t o4 = (size_t)m * H + j;
  size_t oP = (size_t)m * KP + j;
  float2 cz = *(const float2*)&c_z[o4];
  float2 ch = *(const float2*)&c_h[o4];
  float2 tv = *(const float2*)&th[o4];
  short2 tzh = *(const short2*)&hh[oP];
  short2 tzl = *(const short2*)&hl[oP];
  short2 smh = *(const short2*)&shh[oP];
  short2 sml = *(const short2*)&shl[oP];
  float tz0 = bf16tof(tzh.x) + bf16tof(tzl.x);
  float tz1 = bf16tof(tzh.y) + bf16tof(tzl.y);
  float sm0 = bf16tof(smh.x) + bf16tof(sml.x);
  float sm1 = bf16tof(smh.y) + bf16tof(sml.y);
  float z0 = sigmoidf_(cz.x + tz0);
  float z1 = sigmoidf_(cz.y + tz1);
  float p0 = tanhf(ch.x + tv.x);
  float p1 = tanhf(ch.y + tv.y);
  float v0 = (1.f - z0) * sm0 + z0 * p0;
  float v1 = (1.f - z1) * sm1 + z1 * p1;
  if (m == 0) { v0 = 0.f; v1 = 0.f; }
  short2 h2, l2;
  bf16split(v0, h2.x, l2.x); bf16split(v1, h2.y, l2.y);
  *(short2*)&hh[oP] = h2; *(short2*)&hl[oP] = l2;
}

// AcatS[n] = [split(emb[fnode[n]]), split(sum_k h[ng[n,k]])], stride 960, pad zeros
__global__ void k_nodecat(const float* __restrict__ emb,
                          const int* __restrict__ fnode,
                          const short* __restrict__ hh, const short* __restrict__ hl,
                          const int* __restrict__ ng,
                          short* __restrict__ Ah, short* __restrict__ Al) {
  int n = blockIdx.x, t = threadIdx.x, j = t * 2;
  if (j < H) {
    float2 v = *(const float2*)&emb[(size_t)fnode[n] * H + j];
    short2 h2, l2;
    bf16split(v.x, h2.x, l2.x); bf16split(v.y, h2.y, l2.y);
    size_t o = (size_t)n * KP2 + j;
    *(short2*)&Ah[o] = h2; *(short2*)&Al[o] = l2;

    const int* e = ng + (size_t)n * KN;
    float s0 = 0.f, s1 = 0.f;
#pragma unroll
    for (int k = 0; k < KN; ++k) {
      size_t oP = (size_t)e[k] * KP + j;
      short2 ph = *(const short2*)&hh[oP];
      short2 pl = *(const short2*)&hl[oP];
      s0 += bf16tof(ph.x) + bf16tof(pl.x);
      s1 += bf16tof(ph.y) + bf16tof(pl.y);
    }
    bf16split(s0, h2.x, l2.x); bf16split(s1, h2.y, l2.y);
    o = (size_t)n * KP2 + H + j;
    *(short2*)&Ah[o] = h2; *(short2*)&Al[o] = l2;
  }
  if (t < 30) {  // zero pad cols [900, 960)
    short2 z2; z2.x = 0; z2.y = 0;
    size_t o = (size_t)n * KP2 + H2 + t * 2;
    *(short2*)&Ah[o] = z2; *(short2*)&Al[o] = z2;
  }
}

// ---------------- launch ----------------

extern "C" void kernel_launch(void* const* d_in, const int* in_sizes, int n_in,
                              void* d_out, int out_size, void* d_ws, size_t ws_size,
                              hipStream_t stream) {
  (void)in_sizes; (void)n_in; (void)out_size; (void)ws_size;

  const int*   fnode      = (const int*)d_in[0];
  const int*   fmess      = (const int*)d_in[1];
  const int*   node_graph = (const int*)d_in[2];
  const int*   mess_graph = (const int*)d_in[3];
  const float* emb        = (const float*)d_in[4];
  const float* Wz         = (const float*)d_in[5];
  const float* bz         = (const float*)d_in[6];
  const float* Wr         = (const float*)d_in[7];
  const float* Ur         = (const float*)d_in[8];
  const float* bu         = (const float*)d_in[9];
  const float* Wh         = (const float*)d_in[10];
  const float* bh         = (const float*)d_in[11];
  const float* Wo         = (const float*)d_in[12];
  const float* bo         = (const float*)d_in[13];

  const size_t Msz = (size_t)NMESS * H;   // 4,608,450 floats

  // ---- workspace: 4 f32 buffers + 5 bf16 planes = 123.5 MB ----
  float* W   = (float*)d_ws;
  float* c_z = W;
  float* c_h = W + 1 * Msz;
  float* r1b = W + 2 * Msz;
  float* g   = W + 3 * Msz;          // Ur output, then t_h
  short* P   = (short*)(W + 4 * Msz);
  short* hSh  = P;                   // h hi
  short* hSl  = P + 1 * PSZ;         // h lo
  short* shSh = P + 2 * PSZ;         // sum_h hi   (later Acat hi, stride 960)
  short* shSl = P + 3 * PSZ;         // sum_h lo   (later Acat lo)
  short* ghSh = P + 4 * PSZ;         // sum_gh hi  (also eS hi)

  // ---- d_out messages region: idx + split weights + 1 plane (wiped last) ----
  char*  scr    = (char*)d_out + (size_t)NNODE * H * 4;
  int*   idxM   = (int*)scr;                           // 40,964 B
  short* wbase  = (short*)(scr + 41024);
  const size_t WS = (size_t)512 * KP;                  // 245,760 shorts
  short* BtWzTh = wbase + 0*WS;  short* BtWzTl = wbase + 1*WS;
  short* BtWhTh = wbase + 2*WS;  short* BtWhTl = wbase + 3*WS;
  short* BtWrh  = wbase + 4*WS;  short* BtWrl  = wbase + 5*WS;
  short* BtUrh  = wbase + 6*WS;  short* BtUrl  = wbase + 7*WS;
  short* BtWzBh = wbase + 8*WS;  short* BtWzBl = wbase + 9*WS;
  short* BtWhBh = wbase + 10*WS; short* BtWhBl = wbase + 11*WS;
  short* BtWoh  = wbase + 12*WS;
  short* BtWol  = BtWoh + (size_t)512 * KP2;
  short* ghSl   = BtWol + (size_t)512 * KP2;           // 5th+1 plane (sum_gh lo / eS lo)

  // zero planes (pad rows/cols must be 0) + d_out scratch region
  hipMemsetAsync(P, 0, 5 * PSZ * sizeof(short), stream);
  hipMemsetAsync(scr, 0, Msz * sizeof(float), stream);

  k_build_idx<<<(NMESS + 255) / 256, 256, 0, stream>>>(fnode, fmess, idxM);

  dim3 gT(KP / 32, 16), gT2(KP2 / 32, 16);
  k_wT<<<gT,  256, 0, stream>>>(Wz,                  H, BtWzTh, BtWzTl, KP);
  k_wT<<<gT,  256, 0, stream>>>(Wz + (size_t)H * H,  H, BtWzBh, BtWzBl, KP);
  k_wT<<<gT,  256, 0, stream>>>(Wh,                  H, BtWhTh, BtWhTl, KP);
  k_wT<<<gT,  256, 0, stream>>>(Wh + (size_t)H * H,  H, BtWhBh, BtWhBl, KP);
  k_wT<<<gT,  256, 0, stream>>>(Wr,                  H, BtWrh,  BtWrl,  KP);
  k_wT<<<gT,  256, 0, stream>>>(Ur,                  H, BtUrh,  BtUrl,  KP);
  k_wT<<<gT2, 256, 0, stream>>>(Wo,                 H2, BtWoh,  BtWol,  KP2);

  // fmess_e split (into ghS pair, dead until gather_gsum)
  k_embsplit<<<NMESS, 256, 0, stream>>>(emb, idxM, ghSh, ghSl);

  dim3 gB(8, MPAD / BM);   // (8, 81)
  gemm2<0,0><<<gB, 256, 0, stream>>>(ghSh, ghSl, KP, BtWzTh, BtWzTl, bz, c_z, nullptr, nullptr, H, NMESS, H);
  gemm2<0,0><<<gB, 256, 0, stream>>>(ghSh, ghSl, KP, BtWhTh, BtWhTl, bh, c_h, nullptr, nullptr, H, NMESS, H);
  gemm2<0,0><<<gB, 256, 0, stream>>>(ghSh, ghSl, KP, BtWrh,  BtWrl,  bu, r1b, nullptr, nullptr, H, NMESS, H);

  for (int d = 0; d < 8; ++d) {
    k_gather_sum<<<NMESS, 256, 0, stream>>>(hSh, hSl, mess_graph, shSh, shSl);
    gemm2<0,0><<<gB, 256, 0, stream>>>(hSh, hSl, KP, BtUrh, BtUrl, nullptr, g, nullptr, nullptr, H, NMESS, H);
    k_gather_gsum<<<NMESS, 256, 0, stream>>>(hSh, hSl, g, r1b, mess_graph, ghSh, ghSl);
    // t_h -> g (f32, g dead) ; t_z -> h planes (old h dead)
    gemm2<0,0><<<gB, 256, 0, stream>>>(ghSh, ghSl, KP, BtWhBh, BtWhBl, nullptr, g, nullptr, nullptr, H, NMESS, H);
    gemm2<0,1><<<gB, 256, 0, stream>>>(shSh, shSl, KP, BtWzBh, BtWzBl, nullptr, nullptr, hSh, hSl, KP, NMESS, H);
    k_combine<<<NMESS, 256, 0, stream>>>(c_z, c_h, g, shSh, shSl, hSh, hSl);
  }

  // Acat split into shS pair (stride 960)
  k_nodecat<<<NNODE, 256, 0, stream>>>(emb, fnode, hSh, hSl, node_graph, shSh, shSl);
  dim3 gF(8, NNODE / BM);   // (8, 40)
  gemm2<1,0><<<gF, 256, 0, stream>>>(shSh, shSl, KP2, BtWoh, BtWol, bo, (float*)d_out, nullptr, nullptr, H, NNODE, H);

  // messages output = zeros (wipes idx + weights + ghSl plane) — AFTER final GEMM
  hipMemsetAsync((float*)d_out + (size_t)NNODE * H, 0, Msz * sizeof(float), stream);
}

// Round 5
// 1598.249 us; speedup vs baseline: 3.2915x; 1.2547x over previous
//
#include <hip/hip_runtime.h>
#include <cstdint>
#include <cstddef>

#define H 450
#define H2 900
#define KP 480
#define KP2 960
#define NMESS 10241
#define NNODE 5120
#define MPAD 10368                 // 81 * 128
#define PSZ ((size_t)MPAD * KP)    // plane size in shorts = 4,976,640
#define KM 5
#define KN 6
#define LDI 1350                   // CH row stride (c_z | c_h | r1b)

typedef __attribute__((ext_vector_type(8))) short short8;   // 8 bf16
typedef __attribute__((ext_vector_type(4))) float f32x4;

__device__ __forceinline__ short bf16rne(float f) {
  union { float f; unsigned u; } x; x.f = f;
  unsigned u = x.u;
  u += 0x7FFF + ((u >> 16) & 1);
  return (short)(u >> 16);
}
__device__ __forceinline__ float bf16tof(short s) {
  union { float f; unsigned u; } x;
  x.u = ((unsigned)(unsigned short)s) << 16;
  return x.f;
}
__device__ __forceinline__ void bf16split(float v, short& hi, short& lo) {
  hi = bf16rne(v);
  lo = bf16rne(v - bf16tof(hi));
}
__device__ __forceinline__ float sigmoidf_(float x) {
  return 1.f / (1.f + __expf(-x));
}

// ---------------- split-bf16 MFMA GEMM v3 ----------------
// 512 threads (8 waves, 32x32 wave tiles), double-buffered LDS,
// XCD-chunked block swizzle, optional fused GRU-combine epilogue.
#define BM 128
#define BN 64
#define BK 32
#define LDS_A 40

// OUT: 0 = f32 C (+bias, opt relu)   2 = fused tz->combine, writes h planes
template<int ACT, int OUT>
__global__ __launch_bounds__(512, 4)
void gemm2(const short* __restrict__ Ah, const short* __restrict__ Al, int Kpad,
           const short* __restrict__ Bth, const short* __restrict__ Btl,
           const float* __restrict__ bias,
           float* C, int ldc, int M, int N,
           const float* __restrict__ CHp,   // [M][1350]: c_z | c_h | r1b
           const float* __restrict__ thp,   // [M][450] t_h
           const short* __restrict__ smh, const short* __restrict__ sml, // sum_h planes
           short* oh, short* ol)            // h planes out
{
  __shared__ short As[2][2][BM][LDS_A];   // [buf][plane][row][k]
  __shared__ short Bs[2][2][BN][LDS_A];

  // ---- XCD-chunked bijective swizzle (m204) ----
  const int gx = gridDim.x;
  const int nwg = gx * gridDim.y;
  int lid = blockIdx.y * gx + blockIdx.x;
  const int q = nwg >> 3, r = nwg & 7;
  const int xcd = lid & 7, seq = lid >> 3;
  int sid = (xcd < r) ? (xcd * (q + 1) + seq)
                      : (r * (q + 1) + (xcd - r) * q + seq);
  const int bm = (sid / gx) * BM;
  const int bn = (sid % gx) * BN;

  const int tid  = threadIdx.x;
  const int lane = tid & 63;
  const int wid  = tid >> 6;          // 0..7
  const int wm   = (wid >> 1) * 32;   // 4 row-waves
  const int wn   = (wid & 1) * 32;    // 2 col-waves
  const int l15  = lane & 15;
  const int lk8  = (lane >> 4) * 8;
  const int rr0  = (lane >> 4) * 4;

  // staging assignments
  const int ar = tid >> 2;            // 0..127
  const int ac = (tid & 3) * 8;       // 0,8,16,24
  const int br = tid >> 3;            // 0..63
  const int bc = (tid & 7) * 4;       // 0..28 step 4

  const short* Aph = Ah  + (size_t)(bm + ar) * Kpad + ac;
  const short* Apl = Al  + (size_t)(bm + ar) * Kpad + ac;
  const short* Bph = Bth + (size_t)(bn + br) * Kpad + bc;
  const short* Bpl = Btl + (size_t)(bn + br) * Kpad + bc;
  const int nk = Kpad / BK;

  f32x4 acc[2][2];
#pragma unroll
  for (int i = 0; i < 2; ++i)
#pragma unroll
    for (int j = 0; j < 2; ++j)
#pragma unroll
      for (int t = 0; t < 4; ++t) acc[i][j][t] = 0.f;

  short8 rah, ral;
  short4 rbh, rbl;
  auto LOAD = [&](int t) {
    const int k = t * BK;
    rah = *(const short8*)&Aph[k];
    ral = *(const short8*)&Apl[k];
    rbh = *(const short4*)&Bph[k];
    rbl = *(const short4*)&Bpl[k];
  };
  auto STORE = [&](int b) {
    *(short8*)&As[b][0][ar][ac] = rah;
    *(short8*)&As[b][1][ar][ac] = ral;
    *(short4*)&Bs[b][0][br][bc] = rbh;
    *(short4*)&Bs[b][1][br][bc] = rbl;
  };

  LOAD(0); STORE(0);
  __syncthreads();
  int cur = 0;
  for (int t = 0; t < nk; ++t) {
    if (t + 1 < nk) LOAD(t + 1);
    short8 ah[2], al[2], bh[2], bl[2];
#pragma unroll
    for (int i = 0; i < 2; ++i) {
      ah[i] = *(const short8*)&As[cur][0][wm + i*16 + l15][lk8];
      al[i] = *(const short8*)&As[cur][1][wm + i*16 + l15][lk8];
    }
#pragma unroll
    for (int j = 0; j < 2; ++j) {
      bh[j] = *(const short8*)&Bs[cur][0][wn + j*16 + l15][lk8];
      bl[j] = *(const short8*)&Bs[cur][1][wn + j*16 + l15][lk8];
    }
#pragma unroll
    for (int i = 0; i < 2; ++i)
#pragma unroll
      for (int j = 0; j < 2; ++j) {
        acc[i][j] = __builtin_amdgcn_mfma_f32_16x16x32_bf16(ah[i], bh[j], acc[i][j], 0, 0, 0);
        acc[i][j] = __builtin_amdgcn_mfma_f32_16x16x32_bf16(al[i], bh[j], acc[i][j], 0, 0, 0);
        acc[i][j] = __builtin_amdgcn_mfma_f32_16x16x32_bf16(ah[i], bl[j], acc[i][j], 0, 0, 0);
      }
    if (t + 1 < nk) STORE(cur ^ 1);
    __syncthreads();
    cur ^= 1;
  }

#pragma unroll
  for (int j = 0; j < 2; ++j) {
    int col = bn + wn + j*16 + l15;
    if (col >= N) continue;
    float bv = (OUT == 0 && bias) ? bias[col] : 0.f;
#pragma unroll
    for (int i = 0; i < 2; ++i) {
      int row0 = bm + wm + i*16 + rr0;
#pragma unroll
      for (int rr = 0; rr < 4; ++rr) {
        int row = row0 + rr;
        if (row >= M) continue;
        float v = acc[i][j][rr] + bv;
        if (OUT == 0) {
          if (ACT == 1) v = fmaxf(v, 0.f);
          C[(size_t)row * ldc + col] = v;
        } else {
          // fused: v = t_z ; h = mask*((1-z)*sum_h + z*tanh(c_h + t_h))
          size_t oc = (size_t)row * LDI + col;
          size_t op = (size_t)row * KP + col;
          float z     = sigmoidf_(CHp[oc] + v);
          float sum_h = bf16tof(smh[op]) + bf16tof(sml[op]);
          float pre   = tanhf(CHp[oc + 450] + thp[(size_t)row * H + col]);
          float hv    = (1.f - z) * sum_h + z * pre;
          if (row == 0) hv = 0.f;
          short hi, lo; bf16split(hv, hi, lo);
          oh[op] = hi; ol[op] = lo;
        }
      }
    }
  }
}

// ---------------- weight transpose + bf16 hi/lo split ----------------
// Bt[c][k] = W[k][c] for c < rmax (rows >= Kreal / cols >= H zero-filled)
__global__ __launch_bounds__(256)
void k_wT(const float* __restrict__ W, int Kreal,
          short* __restrict__ Bth, short* __restrict__ Btl, int Kpad, int rmax) {
  __shared__ float T[32][33];
  const int tx = threadIdx.x & 31;
  const int ty = threadIdx.x >> 5;
  const int k0 = blockIdx.x * 32;
  const int c0 = blockIdx.y * 32;
#pragma unroll
  for (int i = 0; i < 4; ++i) {
    int k = k0 + ty + i*8, c = c0 + tx;
    T[ty + i*8][tx] = (k < Kreal && c < H) ? W[(size_t)k * H + c] : 0.f;
  }
  __syncthreads();
#pragma unroll
  for (int i = 0; i < 4; ++i) {
    int c = c0 + ty + i*8, k = k0 + tx;
    if (k < Kpad && c < rmax) {
      short hi, lo;
      bf16split(T[tx][ty + i*8], hi, lo);
      Bth[(size_t)c * Kpad + k] = hi;
      Btl[(size_t)c * Kpad + k] = lo;
    }
  }
}

__global__ void k_biascat(const float* __restrict__ bz, const float* __restrict__ bh,
                          const float* __restrict__ bu, float* __restrict__ biasI) {
  int c = blockIdx.x * blockDim.x + threadIdx.x;
  if (c >= 1408) return;
  float v = 0.f;
  if (c < 450) v = bz[c];
  else if (c < 900) v = bh[c - 450];
  else if (c < 1350) v = bu[c - 900];
  biasI[c] = v;
}

// ---------------- elementwise / gather kernels ----------------

__global__ void k_build_idx(const int* __restrict__ fnode,
                            const int* __restrict__ fmess,
                            int* __restrict__ idxM) {
  int m = blockIdx.x * blockDim.x + threadIdx.x;
  if (m < NMESS) idxM[m] = fnode[fmess[m]];
}

__global__ void k_embsplit(const float* __restrict__ emb,
                           const int* __restrict__ idxM,
                           short* __restrict__ eh, short* __restrict__ el) {
  int m = blockIdx.x, j = threadIdx.x * 2;
  if (j >= H) return;
  float2 v = *(const float2*)&emb[(size_t)idxM[m] * H + j];
  short2 h2, l2;
  bf16split(v.x, h2.x, l2.x); bf16split(v.y, h2.y, l2.y);
  size_t o = (size_t)m * KP + j;
  *(short2*)&eh[o] = h2; *(short2*)&el[o] = l2;
}

// one pass over neighbors: sum_h planes + sum_gh planes
__global__ void k_gather2(const short* __restrict__ hh, const short* __restrict__ hl,
                          const float* __restrict__ g,
                          const float* __restrict__ CHp,   // r1b at +900, stride LDI
                          const int* __restrict__ mg,
                          short* __restrict__ shh, short* __restrict__ shl,
                          short* __restrict__ ghh, short* __restrict__ ghl) {
  int m = blockIdx.x, j = threadIdx.x * 2;
  if (j >= H) return;
  const int* e = mg + (size_t)m * KM;
  float2 rb = *(const float2*)&CHp[(size_t)m * LDI + 900 + j];
  float s0 = 0.f, s1 = 0.f, t0 = 0.f, t1 = 0.f;
#pragma unroll
  for (int k = 0; k < KM; ++k) {
    int ek = e[k];
    size_t oP = (size_t)ek * KP + j;
    float2 gv = *(const float2*)&g[(size_t)ek * H + j];
    short2 ph = *(const short2*)&hh[oP];
    short2 pl = *(const short2*)&hl[oP];
    float h0 = bf16tof(ph.x) + bf16tof(pl.x);
    float h1 = bf16tof(ph.y) + bf16tof(pl.y);
    s0 += h0;                          s1 += h1;
    t0 += sigmoidf_(rb.x + gv.x) * h0; t1 += sigmoidf_(rb.y + gv.y) * h1;
  }
  size_t o = (size_t)m * KP + j;
  short2 h2, l2;
  bf16split(s0, h2.x, l2.x); bf16split(s1, h2.y, l2.y);
  *(short2*)&shh[o] = h2; *(short2*)&shl[o] = l2;
  bf16split(t0, h2.x, l2.x); bf16split(t1, h2.y, l2.y);
  *(short2*)&ghh[o] = h2; *(short2*)&ghl[o] = l2;
}

// Acat planes [n][960] = [split(emb[fnode[n]]), split(sum_k h[ng[n,k]]), 0-pad]
__global__ void k_nodecat(const float* __restrict__ emb,
                          const int* __restrict__ fnode,
                          const short* __restrict__ hh, const short* __restrict__ hl,
                          const int* __restrict__ ng,
                          short* __restrict__ Ah, short* __restrict__ Al) {
  int n = blockIdx.x, t = threadIdx.x, j = t * 2;
  if (j < H) {
    float2 v = *(const float2*)&emb[(size_t)fnode[n] * H + j];
    short2 h2, l2;
    bf16split(v.x, h2.x, l2.x); bf16split(v.y, h2.y, l2.y);
    size_t o = (size_t)n * KP2 + j;
    *(short2*)&Ah[o] = h2; *(short2*)&Al[o] = l2;

    const int* e = ng + (size_t)n * KN;
    float s0 = 0.f, s1 = 0.f;
#pragma unroll
    for (int k = 0; k < KN; ++k) {
      size_t oP = (size_t)e[k] * KP + j;
      short2 ph = *(const short2*)&hh[oP];
      short2 pl = *(const short2*)&hl[oP];
      s0 += bf16tof(ph.x) + bf16tof(pl.x);
      s1 += bf16tof(ph.y) + bf16tof(pl.y);
    }
    bf16split(s0, h2.x, l2.x); bf16split(s1, h2.y, l2.y);
    o = (size_t)n * KP2 + H + j;
    *(short2*)&Ah[o] = h2; *(short2*)&Al[o] = l2;
  }
  if (t < 30) {   // zero cols [900,960)
    short2 z2; z2.x = 0; z2.y = 0;
    size_t o = (size_t)n * KP2 + H2 + t * 2;
    *(short2*)&Ah[o] = z2; *(short2*)&Al[o] = z2;
  }
}

// ---------------- launch ----------------

extern "C" void kernel_launch(void* const* d_in, const int* in_sizes, int n_in,
                              void* d_out, int out_size, void* d_ws, size_t ws_size,
                              hipStream_t stream) {
  (void)in_sizes; (void)n_in; (void)out_size; (void)ws_size;

  const int*   fnode      = (const int*)d_in[0];
  const int*   fmess      = (const int*)d_in[1];
  const int*   node_graph = (const int*)d_in[2];
  const int*   mess_graph = (const int*)d_in[3];
  const float* emb        = (const float*)d_in[4];
  const float* Wz         = (const float*)d_in[5];
  const float* bz         = (const float*)d_in[6];
  const float* Wr         = (const float*)d_in[7];
  const float* Ur         = (const float*)d_in[8];
  const float* bu         = (const float*)d_in[9];
  const float* Wh         = (const float*)d_in[10];
  const float* bh         = (const float*)d_in[11];
  const float* Wo         = (const float*)d_in[12];
  const float* bo         = (const float*)d_in[13];

  // ---- workspace (123.5 MB, proven budget) ----
  float* CH  = (float*)d_ws;                       // [M][1350]: c_z|c_h|r1b
  float* g   = CH + (size_t)NMESS * LDI;           // [M][450]: Ur out, then t_h
  short* P   = (short*)(g + (size_t)NMESS * H);
  short* hSh  = P;
  short* hSl  = P + 1 * PSZ;
  short* shSh = P + 2 * PSZ;     // sum_h hi (later Acat hi, stride 960)
  short* shSl = P + 3 * PSZ;
  short* ghSh = P + 4 * PSZ;     // sum_gh hi (also fmess_e hi)

  // ---- d_out messages region (17.6 of 18.4 MB) ----
  char*  scr   = (char*)d_out + (size_t)NNODE * H * 4;
  int*   idxM  = (int*)scr;                          // 40,964 B
  float* biasI = (float*)(scr + 40976);              // 1408 f32
  short* BtIh  = (short*)(scr + 46608);              // [1408][480]
  short* BtIl  = BtIh  + (size_t)1408 * KP;
  short* BtUrh = BtIl  + (size_t)1408 * KP;          // [512][480] each below
  short* BtUrl = BtUrh + (size_t)512 * KP;
  short* BtZh  = BtUrl + (size_t)512 * KP;           // Wz bottom
  short* BtZl  = BtZh  + (size_t)512 * KP;
  short* BtHh  = BtZl  + (size_t)512 * KP;           // Wh bottom
  short* BtHl  = BtHh  + (size_t)512 * KP;
  short* BtOh  = BtHl  + (size_t)512 * KP;           // Wo [512][960]
  short* BtOl  = BtOh  + (size_t)512 * KP2;
  short* ghSl  = BtOl  + (size_t)512 * KP2;          // sum_gh lo plane

  // zero planes (pads must be 0 / h0 = 0) + scratch region
  hipMemsetAsync(P, 0, 5 * PSZ * sizeof(short), stream);
  hipMemsetAsync(scr, 0, (size_t)NMESS * H * sizeof(float), stream);

  k_build_idx<<<(NMESS + 255) / 256, 256, 0, stream>>>(fnode, fmess, idxM);

  // weight prep: merged invariant [Wz_t | Wh_t | Wr] rows 0/450/900, then GRU/out mats
  dim3 gT(KP / 32, 16), gT2(KP2 / 32, 16);
  k_wT<<<gT,  256, 0, stream>>>(Wz,                  H, BtIh,            BtIl,            KP, 512);
  k_wT<<<gT,  256, 0, stream>>>(Wh,                  H, BtIh + 450 * KP, BtIl + 450 * KP, KP, 512);
  k_wT<<<gT,  256, 0, stream>>>(Wr,                  H, BtIh + 900 * KP, BtIl + 900 * KP, KP, 508);
  k_wT<<<gT,  256, 0, stream>>>(Ur,                  H, BtUrh, BtUrl, KP, 512);
  k_wT<<<gT,  256, 0, stream>>>(Wz + (size_t)H * H,  H, BtZh,  BtZl,  KP, 512);
  k_wT<<<gT,  256, 0, stream>>>(Wh + (size_t)H * H,  H, BtHh,  BtHl,  KP, 512);
  k_wT<<<gT2, 256, 0, stream>>>(Wo,                 H2, BtOh,  BtOl,  KP2, 512);
  k_biascat<<<6, 256, 0, stream>>>(bz, bh, bu, biasI);

  // fmess_e split into ghS pair
  k_embsplit<<<NMESS, 256, 0, stream>>>(emb, idxM, ghSh, ghSl);

  // merged invariant GEMM: CH = fmess_e @ [WzT|WhT|Wr] + [bz|bh|bu]
  dim3 gI(22, MPAD / BM);
  gemm2<0,0><<<gI, 512, 0, stream>>>(ghSh, ghSl, KP, BtIh, BtIl, biasI,
                                     CH, LDI, NMESS, LDI,
                                     nullptr, nullptr, nullptr, nullptr, nullptr, nullptr);

  dim3 gB(8, MPAD / BM);
  for (int d = 0; d < 8; ++d) {
    // g = h @ Ur
    gemm2<0,0><<<gB, 512, 0, stream>>>(hSh, hSl, KP, BtUrh, BtUrl, nullptr,
                                       g, H, NMESS, H,
                                       nullptr, nullptr, nullptr, nullptr, nullptr, nullptr);
    // sum_h & sum_gh planes in one pass
    k_gather2<<<NMESS, 256, 0, stream>>>(hSh, hSl, g, CH, mess_graph, shSh, shSl, ghSh, ghSl);
    // t_h = sum_gh @ WhB -> g (dead)
    gemm2<0,0><<<gB, 512, 0, stream>>>(ghSh, ghSl, KP, BtHh, BtHl, nullptr,
                                       g, H, NMESS, H,
                                       nullptr, nullptr, nullptr, nullptr, nullptr, nullptr);
    // t_z = sum_h @ WzB, fused combine -> h planes
    gemm2<0,2><<<gB, 512, 0, stream>>>(shSh, shSl, KP, BtZh, BtZl, nullptr,
                                       nullptr, 0, NMESS, H,
                                       CH, g, shSh, shSl, hSh, hSl);
  }

  // Acat planes (stride 960) then output GEMM with relu
  k_nodecat<<<NNODE, 256, 0, stream>>>(emb, fnode, hSh, hSl, node_graph, shSh, shSl);
  dim3 gF(8, NNODE / BM);
  gemm2<1,0><<<gF, 512, 0, stream>>>(shSh, shSl, KP2, BtOh, BtOl, bo,
                                     (float*)d_out, H, NNODE, H,
                                     nullptr, nullptr, nullptr, nullptr, nullptr, nullptr);

  // messages output = zeros (wipes idx + weights + ghSl) — AFTER final GEMM
  hipMemsetAsync((float*)d_out + (size_t)NNODE * H, 0, (size_t)NMESS * H * sizeof(float), stream);
}